// Round 6
// baseline (480.902 us; speedup 1.0000x reference)
//
#include <hip/hip_runtime.h>

// VectorQuantizer: inputs [32,256,2048] f32, weight [1024,256] f32
// out0 = quantized [32,256,2048] f32, out1 = argmin indices [65536] (as f32)
//
// Round 12: round 11 (barrier-free loop, 4 blocks/CU) with the W-pointer
// group-boundary advance FIXED. Round 11's bug: the 58368-byte jump to
// (g+1, c=0) was applied after CC==7's load instead of after CC==6's, so
// every group's c=0 prefetch read fragment (R_local+1, c=0) of the SAME
// group -> wrong W rows for one chunk per group -> argmin garbage.
// Correct schedule: preload (0,0); step CC loads frag for step CC+1;
// after CC==6's load of (g,7) the pointer must jump to (g+1,0):
//   adv = (CC==6) ? 65536 - 7*1024 + 1024 = 58368 : 1024.   [THE FIX]
//
// Structure (round 11): t-tile 32; split X (hi+lo) = 32 KB LDS built once in
// the prologue; W double-buffered in REGISTERS from a fragment-ordered
// workspace (1 KB per A-fragment, one coalesced dwordx4 load per lane); wave
// = k-quarter (32k x 32t, 2x2 frags, 12 MFMA/step); NO barriers, no LDS
// writes, no explicit waitcnt in the 64-step loop. ~35 KB LDS -> 4 blocks/CU.
//
// Numerics (verified rounds 2-10, unchanged): dist = fp32( fp32(xnorm+wnorm)
// - fp32(2dot) ), dot = fp16x2-split 3-product MFMA in d-ascending order
// (hi; ah*bl; al*bh), W pre-scaled by 1024 (exact pow2), lo terms scaled 2^24;
// xnorm f64 chunk-partials summed in fixed ascending order then (float);
// argmin strict '<' ascending k + index-min tie-break. Per-element W split
// bytes identical to rounds 5-10 (only their storage ORDER changed).

#define VQ_B   32
#define VQ_D   256
#define VQ_T   2048
#define VQ_K   1024

typedef _Float16 f16x8 __attribute__((ext_vector_type(8)));
typedef _Float16 f16x4 __attribute__((ext_vector_type(4)));
typedef float    f32x4 __attribute__((ext_vector_type(4)));

// ---------------- kernel 1: W prep (64 blocks), verified round-5 arithmetic,
// fragment-ordered store layout:
//   WT[h|l] byte offset = ((R*8 + c)*64 + quad*16 + r16)*16 + j*2
//   where k-row = R*16 + r16, d = c*32 + quad*8 + j.
// A 16x16x32 A-fragment for (row-block R, chunk c) is the contiguous 1 KB at
// ((R*8+c)*1024 + lane*16), lane = quad*16 + r16.
__global__ __launch_bounds__(256) void vq_wprep_kernel(
    const float* __restrict__ w, float* __restrict__ wnorm,
    _Float16* __restrict__ WTh, _Float16* __restrict__ WTl)
{
    __shared__ double ws_[16][16];
    const int tid = threadIdx.x;
    const int kk  = tid >> 4;
    const int dg  = tid & 15;
    const int k   = blockIdx.x * 16 + kk;
    const int R   = k >> 4;
    const int r16 = k & 15;
    const float* src = w + (size_t)k * VQ_D + dg * 16;
    double s = 0.0;
    #pragma unroll
    for (int q = 0; q < 4; ++q) {
        float4 v = *(const float4*)(src + q * 4);
        s += (double)v.x * v.x + (double)v.y * v.y
           + (double)v.z * v.z + (double)v.w * v.w;
        const float e4[4] = {v.x, v.y, v.z, v.w};
        f16x4 hv, lv;
        #pragma unroll
        for (int j = 0; j < 4; ++j) {
            const float es = e4[j] * 1024.0f;          // exact pow2 scale
            const _Float16 h = (_Float16)es;
            hv[j] = h;
            lv[j] = (_Float16)((es - (float)h) * 16777216.0f);
        }
        // d = dg*16 + q*4 + jj: c = dg>>1, quad = (dg&1)*2 + (q>>1),
        // j = (q&1)*4 + jj  -> 8-byte contiguous store
        const size_t off = (size_t)(((R * 8 + (dg >> 1)) * 64
                          + ((dg & 1) * 2 + (q >> 1)) * 16 + r16) * 16)
                          + (q & 1) * 8;
        *(f16x4*)((char*)WTh + off) = hv;
        *(f16x4*)((char*)WTl + off) = lv;
    }
    ws_[kk][dg] = s;
    __syncthreads();
    if (dg == 0) {
        double acc = 0.0;
        #pragma unroll
        for (int g = 0; g < 16; ++g) acc += ws_[kk][g];  // fixed order
        wnorm[k] = (float)acc;
    }
}

// one step: (optionally) load next W frags to regs, read X frags from LDS,
// 12 MFMAs in the verified order. CC is a literal -> all indices static.
// Pointer schedule: step CC loads the fragment for step CC+1; the jump to
// (g+1, c=0) happens after CC==6's load (THE round-12 fix).
#define VQ_STEP(CUR_H, CUR_L, NXT_H, NXT_L, CC, LAST)                      \
  {                                                                        \
    if (!(LAST)) {                                                         \
      _Pragma("unroll")                                                    \
      for (int fm = 0; fm < 2; ++fm) {                                     \
        NXT_H[fm] = *(const f16x8*)pwh[fm];                                \
        NXT_L[fm] = *(const f16x8*)pwl[fm];                                \
      }                                                                    \
      const long adv_ = ((CC) == 6) ? 58368L : 1024L;                      \
      pwh[0] += adv_; pwh[1] += adv_; pwl[0] += adv_; pwl[1] += adv_;      \
    }                                                                      \
    f16x8 bh_[2], bl_[2];                                                  \
    _Pragma("unroll")                                                      \
    for (int fn = 0; fn < 2; ++fn) {                                       \
      const int xoff_ = (((CC) * 4 + quad) * 32 + fn * 16 + m16) * 16;     \
      bh_[fn] = *(const f16x8*)(Xh + xoff_);                               \
      bl_[fn] = *(const f16x8*)(Xl + xoff_);                               \
    }                                                                      \
    _Pragma("unroll")                                                      \
    for (int fm = 0; fm < 2; ++fm)                                         \
      _Pragma("unroll")                                                    \
      for (int fn = 0; fn < 2; ++fn) {                                     \
        acch[fm][fn] = __builtin_amdgcn_mfma_f32_16x16x32_f16(             \
            CUR_H[fm], bh_[fn], acch[fm][fn], 0, 0, 0);                    \
        accl[fm][fn] = __builtin_amdgcn_mfma_f32_16x16x32_f16(             \
            CUR_H[fm], bl_[fn], accl[fm][fn], 0, 0, 0);                    \
        accl[fm][fn] = __builtin_amdgcn_mfma_f32_16x16x32_f16(             \
            CUR_L[fm], bh_[fn], accl[fm][fn], 0, 0, 0);                    \
      }                                                                    \
  }

// ---------------- kernel 2: barrier-free MFMA distance GEMM + argmin + gather
// 2048 blocks (b = blk>>6, t-tile 32), 4 waves, wave wm = k-quarter.
// LDS: [0,16K) Xh  [16K,32K) Xl   (layout ((c*4+quad)*32 + t)*16B)
//      [32K,34K) xs f64[8][32]    (prologue partials; reused for argmin)
//      [34K, +128) xns f32[32]
__global__ __launch_bounds__(256, 4) void vq_mfma_kernel(
    const _Float16* __restrict__ WTh, const _Float16* __restrict__ WTl,
    const float* __restrict__ inp,
    const float* __restrict__ wnorm,
    const float* __restrict__ w,
    float* __restrict__ outq, float* __restrict__ outi)
{
    __shared__ alignas(16) char lds[32768 + 2048 + 128];
    char* Xh = lds;
    char* Xl = lds + 16384;
    double* xs  = (double*)(lds + 32768);
    float*  xns = (float*)(lds + 32768 + 2048);

    const int tid  = threadIdx.x;
    const int lane = tid & 63;
    const int wv   = tid >> 6;                // wave 0..3 = k-quarter wm
    const int m16  = lane & 15;
    const int quad = lane >> 4;
    const int wm   = wv;
    const int b    = blockIdx.x >> 6;
    const int tt0  = (blockIdx.x & 63) * 32;
    const long bt  = (long)b * VQ_T + tt0;

    // ---- prologue: load raw X once, split (verified expression), stage to
    // LDS; f64 xnorm chunk-partials, combined in fixed ascending-chunk order.
    {
        const int po = tid >> 5;              // d-chunk 0..7
        const int pt = tid & 31;              // t
        double xacc = 0.0;
        const float* xp = inp + ((size_t)b * VQ_D + po * 32) * VQ_T + tt0 + pt;
        #pragma unroll
        for (int q = 0; q < 4; ++q) {
            float xv[8];
            #pragma unroll
            for (int j = 0; j < 8; ++j)
                xv[j] = xp[(size_t)(q * 8 + j) * VQ_T];
            f16x8 hv, lv;
            #pragma unroll
            for (int j = 0; j < 8; ++j) {
                const float x = xv[j];
                xacc += (double)x * (double)x;         // ascending d
                const _Float16 h = (_Float16)x;
                hv[j] = h;
                lv[j] = (_Float16)((x - (float)h) * 16777216.0f);
            }
            const int off = ((po * 4 + q) * 32 + pt) * 16;
            *(f16x8*)(Xh + off) = hv;
            *(f16x8*)(Xl + off) = lv;
        }
        xs[po * 32 + pt] = xacc;
    }
    __syncthreads();
    if (tid < 32) {
        double s = xs[tid];
        #pragma unroll
        for (int o = 1; o < 8; ++o) s += xs[o * 32 + tid];  // fixed order
        xns[tid] = (float)s;
    }
    __syncthreads();

    float xnr[2];
    #pragma unroll
    for (int f = 0; f < 2; ++f)
        xnr[f] = xns[f * 16 + m16];

    // ---- W fragment pointers (fragment-ordered workspace):
    // byte = g*65536 + (wm*2+fm)*8192 + c*1024 + lane*16
    const char* pwh[2];
    const char* pwl[2];
    #pragma unroll
    for (int fm = 0; fm < 2; ++fm) {
        const size_t base = (size_t)(wm * 2 + fm) * 8192 + (size_t)lane * 16;
        pwh[fm] = (const char*)WTh + base;
        pwl[fm] = (const char*)WTl + base;
    }
    // preload step 0 into buffer A
    f16x8 aAh[2], aAl[2], aBh[2], aBl[2];
    #pragma unroll
    for (int fm = 0; fm < 2; ++fm) {
        aAh[fm] = *(const f16x8*)pwh[fm];
        aAl[fm] = *(const f16x8*)pwl[fm];
    }
    pwh[0] += 1024; pwh[1] += 1024; pwl[0] += 1024; pwl[1] += 1024;

    float bestv[2] = {3.0e38f, 3.0e38f};
    int   besti[2] = {0, 0};
    f32x4 acch[2][2], accl[2][2];

    // ---- main loop: 8 k-groups x 8 d-chunks, NO barriers, no LDS writes.
    for (int g = 0; g < 8; ++g) {
        float wnr[2][4];
        #pragma unroll
        for (int fm = 0; fm < 2; ++fm)
            #pragma unroll
            for (int r = 0; r < 4; ++r)
                wnr[fm][r] = wnorm[g * 128 + wm * 32 + fm * 16 + quad * 4 + r];

        #pragma unroll
        for (int fm = 0; fm < 2; ++fm)
            #pragma unroll
            for (int fn = 0; fn < 2; ++fn) {
                acch[fm][fn] = (f32x4){0.f, 0.f, 0.f, 0.f};
                accl[fm][fn] = (f32x4){0.f, 0.f, 0.f, 0.f};
            }

        VQ_STEP(aAh, aAl, aBh, aBl, 0, false)
        VQ_STEP(aBh, aBl, aAh, aAl, 1, false)
        VQ_STEP(aAh, aAl, aBh, aBl, 2, false)
        VQ_STEP(aBh, aBl, aAh, aAl, 3, false)
        VQ_STEP(aAh, aAl, aBh, aBl, 4, false)
        VQ_STEP(aBh, aBl, aAh, aAl, 5, false)
        VQ_STEP(aAh, aAl, aBh, aBl, 6, false)
        VQ_STEP(aBh, aBl, aAh, aAl, 7, (g == 7))

        // scores: reference fp32 rounding chain; strict '<' over ascending k
        #pragma unroll
        for (int fm = 0; fm < 2; ++fm) {
            #pragma unroll
            for (int r = 0; r < 4; ++r) {
                const int kg = g * 128 + wm * 32 + fm * 16 + quad * 4 + r;
                const float wnk = wnr[fm][r];
                #pragma unroll
                for (int fn = 0; fn < 2; ++fn) {
                    const float t1 = xnr[fn] + wnk;
                    const float d2 = (acch[fm][fn][r]
                                      + accl[fm][fn][r] * 5.9604644775390625e-8f)
                                     * 0.001953125f;
                    const float sc = t1 - d2;
                    if (sc < bestv[fn]) { bestv[fn] = sc; besti[fn] = kg; }
                }
            }
        }
    }

    // cross-lane argmin: lanes {c, c+16, c+32, c+48} share a t-column
    float rv[2]; int ri[2];
    #pragma unroll
    for (int fn = 0; fn < 2; ++fn) {
        float bv = bestv[fn]; int bi = besti[fn];
        #pragma unroll
        for (int mask = 16; mask <= 32; mask <<= 1) {
            const float ov = __shfl_xor(bv, mask, 64);
            const int   oi = __shfl_xor(bi, mask, 64);
            if (ov < bv || (ov == bv && oi < bi)) { bv = ov; bi = oi; }
        }
        rv[fn] = bv; ri[fn] = bi;
    }

    // cross-wave (4 k-quarters, ascending) reduce via LDS overlay (X dead)
    __syncthreads();
    float* sv  = (float*)lds;                // [4][32]
    int*   si_ = (int*)(lds + 512);          // [4][32]
    int*   sif = (int*)(lds + 1536);         // [32]
    if (quad == 0) {
        #pragma unroll
        for (int fn = 0; fn < 2; ++fn) {
            const int tl = fn * 16 + m16;
            sv[wm * 32 + tl] = rv[fn];
            si_[wm * 32 + tl] = ri[fn];
        }
    }
    __syncthreads();
    if (tid < 32) {
        float bv = sv[tid]; int bi = si_[tid];
        #pragma unroll
        for (int wq = 1; wq < 4; ++wq) {
            const float v = sv[wq * 32 + tid];
            const int   i = si_[wq * 32 + tid];
            if (v < bv || (v == bv && i < bi)) { bv = v; bi = i; }
        }
        sif[tid] = bi;
        outi[bt + tid] = (float)bi;
    }
    __syncthreads();

    // quantized output: outq[b][d][t] = w[best[t]][d]  (verified epilogue)
    {
        const int t  = tid & 31;
        const int dg = tid >> 5;
        const int bi = sif[t];
        const float* wrow = w + (size_t)bi * VQ_D + dg * 32;
        float* obase = outq + ((size_t)b * VQ_D + (size_t)dg * 32) * VQ_T + tt0 + t;
        #pragma unroll 4
        for (int dd = 0; dd < 32; dd += 4) {
            float4 v = *(const float4*)(wrow + dd);
            obase[(size_t)(dd + 0) * VQ_T] = v.x;
            obase[(size_t)(dd + 1) * VQ_T] = v.y;
            obase[(size_t)(dd + 2) * VQ_T] = v.z;
            obase[(size_t)(dd + 3) * VQ_T] = v.w;
        }
    }
}

extern "C" void kernel_launch(void* const* d_in, const int* in_sizes, int n_in,
                              void* d_out, int out_size, void* d_ws, size_t ws_size,
                              hipStream_t stream) {
    const float* inp = (const float*)d_in[0];
    const float* w   = (const float*)d_in[1];
    float* outq  = (float*)d_out;
    float* outi  = outq + (size_t)VQ_B * VQ_D * VQ_T;   // indices appended flat

    float*    wnorm = (float*)d_ws;                     // [1024]
    _Float16* WTh   = (_Float16*)(wnorm + VQ_K);        // [1024*256], frag order
    _Float16* WTl   = WTh + (size_t)VQ_K * VQ_D;
    // total ws use: ~1.03 MB

    vq_wprep_kernel<<<dim3(VQ_K / 16), dim3(256), 0, stream>>>(w, wnorm, WTh, WTl);
    vq_mfma_kernel<<<dim3(VQ_B * (VQ_T / 32)), dim3(256), 0, stream>>>(
        WTh, WTl, inp, wnorm, w, outq, outi);
}

// Round 7
// 247.092 us; speedup vs baseline: 1.9462x; 1.9462x over previous
//
#include <hip/hip_runtime.h>

// VectorQuantizer: inputs [32,256,2048] f32, weight [1024,256] f32
// out0 = quantized [32,256,2048] f32, out1 = argmin indices [65536] (as f32)
//
// Round 13: FUSED round-0. Lessons: (r12) free-running register W-loads lose
// L2 temporal alignment -> 1 GB HBM fetch; barrier-paced global_load_lds
// staging keeps FETCH at ~50 MB (r10). (r8-12) the reg/LDS triangle caps
// occupancy at ~8 waves/CU for this algorithm; round-0's t=128 loop (131.7us,
// MfmaUtil 33%) is the best frontier point. Remaining lever: the ~44us
// separate X-prep dispatch.
//   - The MFMA loop only reads its OWN (b, t128) slice of Xh/Xl/xnorm ->
//     each block's prologue writes that slice to the global workspace, then
//     the VERBATIM round-0 loop runs (byte-identical staging addresses).
//     Intra-block visibility of own global writes: __syncthreads (workgroup
//     memory fence; same CU -> same L1/L2).
//   - Prologue vectorized: thread owns 4 consecutive t-cols x 32 d; float4
//     loads (1/4 the instructions of round-0's scalar prep, same bytes).
//     xnorm: 8 f64 slice-partials per t (d-ascending within and across
//     slices), combined ascending then (float) — grouping precedented by
//     round 12's passing prologue (absmax 3.8e-6).
//   - X re-reads (8x per kg) now hit the same-XCD L2 (written locally).
// W-prep stays a tiny 64-block kernel (row-major Wh/Wl, verified r5-r10).
//
// Numerics (verified rounds 2-12): dist = fp32( fp32(xnorm+wnorm) -
// fp32(2dot) ), dot = fp16x2-split 3-product MFMA chunk-ascending
// (hi; ah*bl; al*bh), W pre-scaled by 1024 (exact pow2), lo terms scaled
// 2^24; argmin strict '<' ascending k + index-min tie-break.

#define VQ_B   32
#define VQ_D   256
#define VQ_T   2048
#define VQ_K   1024

typedef _Float16 f16x8 __attribute__((ext_vector_type(8)));
typedef _Float16 f16x4 __attribute__((ext_vector_type(4)));
typedef float    f32x4 __attribute__((ext_vector_type(4)));

#define GLOAD_LDS16(gaddr, laddr) \
  __builtin_amdgcn_global_load_lds((const __attribute__((address_space(1))) void*)(gaddr), \
                                   (__attribute__((address_space(3))) void*)(laddr), 16, 0, 0)

// ---------------- kernel 1: W prep only (64 blocks), verified round-5 body,
// row-major Wh/Wl layout (as rounds 6-10).
__global__ __launch_bounds__(256) void vq_wprep_kernel(
    const float* __restrict__ w, float* __restrict__ wnorm,
    _Float16* __restrict__ Wh, _Float16* __restrict__ Wl)
{
    __shared__ double ws_[16][16];
    const int tid = threadIdx.x;
    const int kk  = tid >> 4;
    const int dg  = tid & 15;
    const int k   = blockIdx.x * 16 + kk;
    const float* src = w + (size_t)k * VQ_D + dg * 16;
    double s = 0.0;
    #pragma unroll
    for (int q = 0; q < 4; ++q) {
        float4 v = *(const float4*)(src + q * 4);
        s += (double)v.x * v.x + (double)v.y * v.y
           + (double)v.z * v.z + (double)v.w * v.w;
        const float e4[4] = {v.x, v.y, v.z, v.w};
        f16x4 hv, lv;
        #pragma unroll
        for (int j = 0; j < 4; ++j) {
            const float es = e4[j] * 1024.0f;          // exact pow2 scale
            const _Float16 h = (_Float16)es;
            hv[j] = h;
            lv[j] = (_Float16)((es - (float)h) * 16777216.0f);
        }
        *(f16x4*)(Wh + (size_t)k * VQ_D + dg * 16 + q * 4) = hv;
        *(f16x4*)(Wl + (size_t)k * VQ_D + dg * 16 + q * 4) = lv;
    }
    ws_[kk][dg] = s;
    __syncthreads();
    if (dg == 0) {
        double acc = 0.0;
        #pragma unroll
        for (int g = 0; g < 16; ++g) acc += ws_[kk][g];  // fixed order
        wnorm[k] = (float)acc;
    }
}

// ---------------- kernel 2: fused prologue + round-0 MFMA loop (verbatim)
// 512 blocks, 4 waves (2x2), 128t x 128k tile, 64 linear (k0,d0) steps,
// double-buffered 2x32KB staging, one barrier per step.
__global__ __launch_bounds__(256, 2) void vq_mfma_kernel(
    const _Float16* __restrict__ Wh, const _Float16* __restrict__ Wl,
    const float* __restrict__ inp,
    _Float16* __restrict__ Xh, _Float16* __restrict__ Xl,
    float* __restrict__ wnorm, float* __restrict__ xnorm,
    const float* __restrict__ w,
    float* __restrict__ outq, float* __restrict__ outi)
{
    __shared__ alignas(16) char stg[2][32768];   // 2 x 32 regions x 1024 B
    const int tid  = threadIdx.x;
    const int lane = tid & 63;
    const int wv   = tid >> 6;                // wave 0..3
    const int m16  = lane & 15;
    const int quad = lane >> 4;
    const int wm   = wv & 1;                  // k half (waves 0/1), lo/hi sel
    const int wn   = wv >> 1;                 // t half
    const int b    = blockIdx.x >> 4;
    const int tt0  = (blockIdx.x & 15) * 128;
    const long bt  = (long)b * VQ_T + tt0;

    // ---- fused prologue: stage this block's (b, tt0..tt0+128) X slice to
    // the global workspace (split bytes identical to the retired prep), and
    // compute xnorm (f64 slice-partials, d-ascending, combined ascending).
    {
        double* xpart = (double*)stg;         // [8][128] f64 overlay, 8 KB
        const int t4 = (tid & 31) * 4;        // 4 consecutive t-cols
        const int ds = tid >> 5;              // d-slice 0..7 (dc = ds*4..+4)
        const float* p = inp + (size_t)b * VQ_D * VQ_T + tt0 + t4;
        double s4[4] = {0.0, 0.0, 0.0, 0.0};
        #pragma unroll
        for (int dc = ds * 4; dc < ds * 4 + 4; ++dc) {
            f16x8 hvv[4], lvv[4];
            #pragma unroll
            for (int j = 0; j < 8; ++j) {
                const float4 v = *(const float4*)(p + (size_t)(dc * 8 + j) * VQ_T);
                const float xx[4] = {v.x, v.y, v.z, v.w};
                #pragma unroll
                for (int tt = 0; tt < 4; ++tt) {
                    const float x = xx[tt];
                    s4[tt] += (double)x * (double)x;       // ascending d per t
                    const _Float16 h = (_Float16)x;
                    hvv[tt][j] = h;
                    lvv[tt][j] = (_Float16)((x - (float)h) * 16777216.0f);
                }
            }
            #pragma unroll
            for (int tt = 0; tt < 4; ++tt) {
                const size_t off = (((size_t)b * 32 + dc) * VQ_T + tt0 + t4 + tt) * 8;
                *(f16x8*)(Xh + off) = hvv[tt];             // verified layout
                *(f16x8*)(Xl + off) = lvv[tt];
            }
        }
        #pragma unroll
        for (int tt = 0; tt < 4; ++tt)
            xpart[ds * 128 + t4 + tt] = s4[tt];
        __syncthreads();
        if (tid < 128) {
            double s = xpart[tid];
            #pragma unroll
            for (int sl = 1; sl < 8; ++sl) s += xpart[sl * 128 + tid]; // asc.
            xnorm[(size_t)b * VQ_T + tt0 + tid] = (float)s;
        }
        __syncthreads();   // xnorm/Xh/Xl visible in-block; xpart overlay dead
    }

    // ---- from here on: VERBATIM round-0 loop (byte-identical staging).
    // xnorm for this lane's 4 t-columns (constant across k)
    float xnr[4];
    #pragma unroll
    for (int fn = 0; fn < 4; ++fn)
        xnr[fn] = xnorm[bt + wn * 64 + fn * 16 + m16];

    // 8 staging source pointers per wave: wave0=Wh, wave1=Wl, wave2=Xh, wave3=Xl
    const char* gp[8];
    #pragma unroll
    for (int i = 0; i < 8; ++i) {
        const int hf = i >> 2, f = i & 3;
        if (wv < 2) {
            const char* baseW = (const char*)((wv & 1) ? Wl : Wh);
            gp[i] = baseW + (size_t)(hf * 64 + f * 16 + m16) * 512 + quad * 16;
        } else {
            const char* baseX = (const char*)((wv & 1) ? Xl : Xh);
            // chunk layout: byte addr = ((b*32 + dc0+quad)*2048 + t_row)*16
            gp[i] = baseX + (((size_t)b * 32 + quad) * 2048
                             + (tt0 + hf * 64 + f * 16 + m16)) * 16;
        }
    }
    // advance after issuing step q: W +64B (32 halves), X +4 dchunks;
    // at chunk boundary W jumps k0+=128 and rewinds d, X rewinds d.
    auto advance = [&](int q) {
        if ((q & 7) == 7) {
            #pragma unroll
            for (int i = 0; i < 8; ++i)
                gp[i] += (wv < 2) ? (long)(65536 - 448) : (long)(-7) * 131072;
        } else {
            #pragma unroll
            for (int i = 0; i < 8; ++i)
                gp[i] += (wv < 2) ? 64L : 131072L;
        }
    };

    float bestv[4] = {3.0e38f, 3.0e38f, 3.0e38f, 3.0e38f};
    int   besti[4] = {0, 0, 0, 0};
    f32x4 acch[4][4], accl[4][4];

    // prologue: issue step 0 into buffer 0
    #pragma unroll
    for (int i = 0; i < 8; ++i)
        GLOAD_LDS16(gp[i], &stg[0][(wv * 8 + i) * 1024]);
    advance(0);

    for (int s = 0; s < 64; ++s) {
        const int cur = s & 1;
        if ((s & 7) == 0) {
            #pragma unroll
            for (int fm = 0; fm < 4; ++fm)
                #pragma unroll
                for (int fn = 0; fn < 4; ++fn) {
                    acch[fm][fn] = (f32x4){0.f, 0.f, 0.f, 0.f};
                    accl[fm][fn] = (f32x4){0.f, 0.f, 0.f, 0.f};
                }
        }
        __syncthreads();            // drains vmcnt -> stg[cur] resident
        if (s < 63) {               // prefetch step s+1 into the other buffer
            #pragma unroll
            for (int i = 0; i < 8; ++i)
                GLOAD_LDS16(gp[i], &stg[cur ^ 1][(wv * 8 + i) * 1024]);
            advance(s + 1);
        }

        const char* base = stg[cur];
        f16x8 ah[4], al[4], bh[4], bl[4];
        #pragma unroll
        for (int f = 0; f < 4; ++f) {
            ah[f] = *(const f16x8*)(base + ((wm * 4 + f)) * 1024 + lane * 16);
            al[f] = *(const f16x8*)(base + ((8 + wm * 4 + f)) * 1024 + lane * 16);
            bh[f] = *(const f16x8*)(base + ((16 + wn * 4 + f)) * 1024 + lane * 16);
            bl[f] = *(const f16x8*)(base + ((24 + wn * 4 + f)) * 1024 + lane * 16);
        }
        #pragma unroll
        for (int fm = 0; fm < 4; ++fm)
            #pragma unroll
            for (int fn = 0; fn < 4; ++fn) {
                acch[fm][fn] = __builtin_amdgcn_mfma_f32_16x16x32_f16(
                    ah[fm], bh[fn], acch[fm][fn], 0, 0, 0);
                accl[fm][fn] = __builtin_amdgcn_mfma_f32_16x16x32_f16(
                    ah[fm], bl[fn], accl[fm][fn], 0, 0, 0);
                accl[fm][fn] = __builtin_amdgcn_mfma_f32_16x16x32_f16(
                    al[fm], bh[fn], accl[fm][fn], 0, 0, 0);
            }

        if ((s & 7) == 7) {
            const int k0 = (s >> 3) * 128;
            // scores, reference fp32 rounding chain; strict '<' over ascending
            // k => ties resolve to lowest index (matches np.argmin)
            #pragma unroll
            for (int fm = 0; fm < 4; ++fm) {
                #pragma unroll
                for (int r = 0; r < 4; ++r) {
                    const int kg = k0 + wm * 64 + fm * 16 + quad * 4 + r;
                    const float wnk = wnorm[kg];
                    #pragma unroll
                    for (int fn = 0; fn < 4; ++fn) {
                        const float t1 = xnr[fn] + wnk;
                        const float d2 = (acch[fm][fn][r]
                                          + accl[fm][fn][r] * 5.9604644775390625e-8f)
                                         * 0.001953125f;
                        const float sc = t1 - d2;
                        if (sc < bestv[fn]) { bestv[fn] = sc; besti[fn] = kg; }
                    }
                }
            }
        }
    }

    // cross-lane argmin: lanes {c, c+16, c+32, c+48} share a t-column
    float rv[4]; int ri[4];
    #pragma unroll
    for (int fn = 0; fn < 4; ++fn) {
        float bv = bestv[fn]; int bi = besti[fn];
        #pragma unroll
        for (int mask = 16; mask <= 32; mask <<= 1) {
            const float ov = __shfl_xor(bv, mask, 64);
            const int   oi = __shfl_xor(bi, mask, 64);
            if (ov < bv || (ov == bv && oi < bi)) { bv = ov; bi = oi; }
        }
        rv[fn] = bv; ri[fn] = bi;
    }

    // cross-wave (wm 0 vs 1) reduce via LDS overlay
    __syncthreads();
    float* sv = (float*)stg[0];              // [2][128]
    int*   si = (int*)(stg[0] + 1024);       // [2][128]
    if (quad == 0) {
        #pragma unroll
        for (int fn = 0; fn < 4; ++fn) {
            const int tl = wn * 64 + fn * 16 + m16;
            sv[wm * 128 + tl] = rv[fn];
            si[wm * 128 + tl] = ri[fn];
        }
    }
    __syncthreads();
    if (tid < 128) {
        const float v0 = sv[tid], v1 = sv[128 + tid];
        const int   i0 = si[tid], i1 = si[128 + tid];
        const int   bi = (v1 < v0 || (v1 == v0 && i1 < i0)) ? i1 : i0;
        si[tid] = bi;
        outi[bt + tid] = (float)bi;
    }
    __syncthreads();

    // quantized output: outq[b][d][t] = w[best[t]][d]  (verified epilogue)
    {
        const int t  = tid & 127;
        const int dh = tid >> 7;
        const int bi = si[t];
        const float* wrow = w + (size_t)bi * VQ_D + dh * 128;
        float* obase = outq + ((size_t)b * VQ_D + (size_t)dh * 128) * VQ_T + tt0 + t;
        #pragma unroll 4
        for (int dd = 0; dd < 128; dd += 4) {
            float4 v = *(const float4*)(wrow + dd);
            obase[(size_t)(dd + 0) * VQ_T] = v.x;
            obase[(size_t)(dd + 1) * VQ_T] = v.y;
            obase[(size_t)(dd + 2) * VQ_T] = v.z;
            obase[(size_t)(dd + 3) * VQ_T] = v.w;
        }
    }
}

extern "C" void kernel_launch(void* const* d_in, const int* in_sizes, int n_in,
                              void* d_out, int out_size, void* d_ws, size_t ws_size,
                              hipStream_t stream) {
    const float* inp = (const float*)d_in[0];
    const float* w   = (const float*)d_in[1];
    float* outq  = (float*)d_out;
    float* outi  = outq + (size_t)VQ_B * VQ_D * VQ_T;   // indices appended flat

    float*    wnorm = (float*)d_ws;                     // [1024]
    float*    xnorm = wnorm + VQ_K;                     // [65536]
    _Float16* Wh    = (_Float16*)(xnorm + VQ_B * VQ_T); // [1024*256]
    _Float16* Wl    = Wh + (size_t)VQ_K * VQ_D;
    _Float16* Xh    = Wl + (size_t)VQ_K * VQ_D;         // [65536*256], chunk layout
    _Float16* Xl    = Xh + (size_t)VQ_B * VQ_T * VQ_D;
    // total ws use: ~68.4 MB (round-0 layout)

    vq_wprep_kernel<<<dim3(VQ_K / 16), dim3(256), 0, stream>>>(w, wnorm, Wh, Wl);
    vq_mfma_kernel<<<dim3(VQ_B * (VQ_T / 128)), dim3(256), 0, stream>>>(
        Wh, Wl, inp, Xh, Xl, wnorm, xnorm, w, outq, outi);
}